// Round 7
// baseline (68.833 us; speedup 1.0000x reference)
//
#include <hip/hip_runtime.h>

// DirectVG: batched progressive box adjustment.
// boxes [B,N,4] f32, gt [B,M,4] f32 -> all_boxes [B,6,N,4] ++ all_sims [B,6,N,M]
//
// Wave = 8 rows (r = lane>>3) x 8 m-groups (g = lane&7). Per iteration:
//   1) stash the wave's 8 box states in wave-local LDS (no barrier needed)
//   2) STREAM sims: lane covers flat floats j*256+4*lane of the wave's packed
//      [8][100] region -> every sims store is a fully lane-contiguous 1024B
//      dwordx4 (fill-kernel pattern). IoUs recomputed from an SoA gt copy with
//      bit-identical op order to the argmax path.
//   3) argmax (in-lane ascending-m strict '>', 3-step shfl over 8 g-lanes,
//      tie -> smaller m == jnp.argmax) + box update.
// NN % 8 == 0 -> wave validity is all-or-nothing; no per-row guards.

#define BB 64
#define NN 1000
#define MM 100
#define NITER 5

__global__ __launch_bounds__(256, 8) void dvg_kernel(
    const float* __restrict__ boxes, const float* __restrict__ gt,
    float* __restrict__ out) {
  __shared__ float4 lgt[MM];                      // AoS for argmax/update
  __shared__ float gx1[MM], gy1[MM], gx2[MM], gy2[MM];  // SoA for streaming
  __shared__ float4 bstash[4][8];                 // per-wave box states

  const int tid = threadIdx.x;
  const int wv = tid >> 6;
  const int lane = tid & 63;
  const int g7 = lane & 7;
  const int r = lane >> 3;
  const int b = blockIdx.x >> 5;            // 32 blocks per batch
  const int row0 = (blockIdx.x & 31) * 32;  // block covers rows row0..row0+31
  const int n0w = row0 + wv * 8;            // wave's first row (multiple of 8)
  const bool wvalid = n0w < NN;             // all 8 rows valid or none
  const int n = n0w + r;
  const int nc = n < NN ? n : NN - 1;

  for (int i = tid; i < MM; i += 256) {
    const float4 q = reinterpret_cast<const float4*>(gt)[b * MM + i];
    lgt[i] = q;
    gx1[i] = q.x; gy1[i] = q.y; gx2[i] = q.z; gy2[i] = q.w;
  }
  __syncthreads();  // the only barrier

  // hoisted gt areas for the argmax path (lane's quads: m = 32k+4*g7+c)
  float areaG[16];
#pragma unroll
  for (int k = 0; k < 4; ++k)
    if (k < 3 || g7 == 0)
#pragma unroll
      for (int c = 0; c < 4; ++c) {
        const float4 q = lgt[32 * k + 4 * g7 + c];
        float a = (q.z - q.x) * (q.w - q.y);
        asm("" : "+v"(a));
        areaG[4 * k + c] = a;
      }

  // per-(lane,j) stream coordinates, invariant across iterations
  int rlj[4], mj[4];
#pragma unroll
  for (int j = 0; j < 4; ++j) {
    const int f = j * 256 + lane * 4;
    rlj[j] = f / 100;
    mj[j] = f - rlj[j] * 100;  // multiple of 4; never straddles a row
  }

  const float4 bx = reinterpret_cast<const float4*>(boxes)[b * NN + nc];
  float b0 = bx.x, b1 = bx.y, b2 = bx.z, b3 = bx.w;

  float* __restrict__ outB = out;                            // [B,6,N,4]
  float* __restrict__ outS = out + (size_t)BB * 6 * NN * 4;  // [B,6,N,M]

  for (int it = 0;; ++it) {
    // forbid hoisting loop-invariant LDS reads into registers (VGPR budget)
    asm volatile("" ::: "memory");

    // 1) stash this iteration's box states (wave-local; same-wave LDS order)
    if (g7 == 0) bstash[wv][r] = make_float4(b0, b1, b2, b3);

    const size_t obase = (size_t)(b * 6 + it) * NN;

    // 2a) boxes out: lanes g7<4 store comp g7 (128B dense per wave)
    if (wvalid && g7 < 4) {
      const float comp = g7 == 0 ? b0 : (g7 == 1 ? b1 : (g7 == 2 ? b2 : b3));
      outB[(obase + n0w + r) * 4 + g7] = comp;
    }

    // 2b) stream sims: 3 full 1024B dwordx4 + one 128B tail per wave
    if (wvalid) {
      float* __restrict__ osb = outS + (obase + n0w) * MM;
#pragma unroll 2
      for (int j = 0; j < 4; ++j) {
        if (j < 3 || lane < 8) {
          const int f = j * 256 + lane * 4;
          const float4 bq = *reinterpret_cast<const float4*>(&bstash[wv][rlj[j]]);
          float ba = (bq.z - bq.x) * (bq.w - bq.y);
          asm("" : "+v"(ba));
          const int m = mj[j];
          const float4 X1 = *reinterpret_cast<const float4*>(&gx1[m]);
          const float4 Y1 = *reinterpret_cast<const float4*>(&gy1[m]);
          const float4 X2 = *reinterpret_cast<const float4*>(&gx2[m]);
          const float4 Y2 = *reinterpret_cast<const float4*>(&gy2[m]);
          float4 d;
#pragma unroll
          for (int c = 0; c < 4; ++c) {
            const float x1 = (&X1.x)[c], y1 = (&Y1.x)[c];
            const float x2 = (&X2.x)[c], y2 = (&Y2.x)[c];
            float ag = (x2 - x1) * (y2 - y1);
            asm("" : "+v"(ag));
            const float w = fmaxf(fminf(bq.z, x2) - fmaxf(bq.x, x1), 0.0f);
            const float h = fmaxf(fminf(bq.w, y2) - fmaxf(bq.y, y1), 0.0f);
            float inter = w * h;
            asm("" : "+v"(inter));
            const float uni = (ba + ag) - inter;
            (&d.x)[c] = inter * __builtin_amdgcn_rcpf(uni);
          }
          *reinterpret_cast<float4*>(&osb[f]) = d;
        }
      }
    }

    if (it == NITER) break;

    // 3) argmax over this row's 100 IoUs (value path, same op order)
    float area = (b2 - b0) * (b3 - b1);
    asm("" : "+v"(area));
    float best = -1.0f;
    int bim = 0;
#pragma unroll
    for (int k = 0; k < 4; ++k) {
      if (k < 3 || g7 == 0) {
#pragma unroll
        for (int c = 0; c < 4; ++c) {
          const int m = 32 * k + 4 * g7 + c;
          const float4 q = lgt[m];  // 8-way broadcast
          const float w = fmaxf(fminf(b2, q.z) - fmaxf(b0, q.x), 0.0f);
          const float h = fmaxf(fminf(b3, q.w) - fmaxf(b1, q.y), 0.0f);
          float inter = w * h;
          asm("" : "+v"(inter));
          const float uni = (area + areaG[4 * k + c]) - inter;
          const float val = inter * __builtin_amdgcn_rcpf(uni);
          const bool t = val > best;  // strict >: first occurrence in-lane
          best = t ? val : best;
          bim = t ? m : bim;
        }
      }
    }
#pragma unroll
    for (int off = 1; off <= 4; off <<= 1) {
      const float ov = __shfl_xor(best, off, 64);
      const int obi = __shfl_xor(bim, off, 64);
      const bool t = (ov > best) || (ov == best && obi < bim);
      best = t ? ov : best;
      bim = t ? obi : bim;
    }

    const float4 gg = lgt[bim];
    const float dcx = (gg.x + gg.z) * 0.5f - (b0 + b2) * 0.5f;
    const float dcy = (gg.y + gg.w) * 0.5f - (b1 + b3) * 0.5f;
    const float dsx = (gg.z - gg.x) - (b2 - b0);
    const float dsy = (gg.w - gg.y) - (b3 - b1);
    float px = 0.45f * dcx;
    asm("" : "+v"(px));
    float py = 0.45f * dcy;
    asm("" : "+v"(py));
    float qx = 0.4f * (dsx - dcx);
    asm("" : "+v"(qx));
    float qy = 0.4f * (dsy - dcy);
    asm("" : "+v"(qy));
    b0 = b0 + px;
    b1 = b1 + py;
    b2 = (b2 + px) + qx;
    b3 = (b3 + py) + qy;
  }
}

extern "C" void kernel_launch(void* const* d_in, const int* in_sizes, int n_in,
                              void* d_out, int out_size, void* d_ws,
                              size_t ws_size, hipStream_t stream) {
  const float* boxes = (const float*)d_in[0];
  const float* gt = (const float*)d_in[1];
  float* out = (float*)d_out;
  // 32 blocks/batch x 4 waves x 8 rows = 1024 row-slots >= 1000
  dvg_kernel<<<BB * 32, 256, 0, stream>>>(boxes, gt, out);
}